// Round 3
// baseline (74.049 us; speedup 1.0000x reference)
//
#include <hip/hip_runtime.h>

#define NSCALES 20
#define BATCH 16
#define PATCH 100
#define IMGS_PER_SCALE 1600
#define TOTAL_IMGS 32000
#define THREADS 256
#define CHUNKPX 4096                     // pixels per block in count_kernel
#define MAXIMG 512                       // >= ceil(4096/9)+1 = 457
#define S2MAX 1681

struct Ptrs   { const float* p[NSCALES]; };
struct Starts { int blkStart[NSCALES]; };

// ---------------------------------------------------------------------------
// Kernel 1: streaming per-image foreground counts.
// Blocks own 4096-pixel chunks of a scale's flat pixel array (img-major),
// independent of image boundaries. 4 px = 3 float4 loads per thread per iter.
// ---------------------------------------------------------------------------
__global__ __launch_bounds__(THREADS)
void count_kernel(Ptrs ptrs, Starts st, int* __restrict__ wsCounts)
{
    const int bid = blockIdx.x;
    int sc = 0;
    #pragma unroll
    for (int k = 1; k < NSCALES; k++) sc += (bid >= st.blkStart[k]) ? 1 : 0;
    const int s  = 3 + 2 * sc;
    const int s2 = s * s;
    const float* __restrict__ x = ptrs.p[sc];
    // exact magic divides (verified n*e < 2^32 for all our ranges)
    const unsigned mS   = 0xFFFFFFFFu / (unsigned)s + 1;
    const unsigned m100 = 0xFFFFFFFFu / 100u + 1;
    const int Ntot = IMGS_PER_SCALE * s2;                 // multiple of 4
    const int P0   = (bid - st.blkStart[sc]) * CHUNKPX;
    const int Pend = min(P0 + CHUNKPX, Ntot);
    const int tid  = threadIdx.x;

    __shared__ float cenL[18 * 3];
    __shared__ int   cntL[MAXIMG];

    const int M0      = (int)__umulhi((unsigned)P0, mS);
    const int Mlast   = (int)__umulhi((unsigned)(Pend - 1), mS);
    const int imgBase = (int)__umulhi((unsigned)M0, mS);
    const int imgLast = (int)__umulhi((unsigned)Mlast, mS);
    const int j0      = (int)__umulhi((unsigned)M0, m100);
    const int jEnd    = (int)__umulhi((unsigned)Mlast, m100);
    const int nImg = imgLast - imgBase + 1;               // <= 457
    const int nj   = jEnd - j0 + 1;                       // <= 15

    for (int t = tid; t < nj * 3; t += THREADS) {
        int j  = j0 + t / 3;
        int ch = t - (t / 3) * 3;
        cenL[t] = x[(size_t)(((j * PATCH + 49) * s + (s >> 1)) * 3 + ch)];
    }
    for (int t = tid; t < nImg; t += THREADS) cntL[t] = 0;
    __syncthreads();

    const float fs = (float)s;
    #pragma unroll
    for (int it = 0; it < CHUNKPX / 4 / THREADS; it++) {  // 4 iterations
        const int pc = P0 + (tid + it * THREADS) * 4;     // first pixel of my 4
        const bool act = (pc < Pend);
        int iA = -1, cA = 0, iB = -1, cB = 0;
        if (act) {
            const float4* q4 = (const float4*)(x + (size_t)pc * 3);
            float4 a = q4[0], b = q4[1], c = q4[2];
            float v0=a.x,v1=a.y,v2=a.z,v3=a.w,v4=b.x,v5=b.y,v6=b.z,v7=b.w,
                  v8=c.x,v9=c.y,v10=c.z,v11=c.w;
            int im[4], fg[4];
            #pragma unroll
            for (int q = 0; q < 4; q++) {
                int P   = pc + q;
                int M   = (int)__umulhi((unsigned)P, mS);
                int img = (int)__umulhi((unsigned)M, mS);
                int j   = (int)__umulhi((unsigned)M, m100);
                const float* ce = &cenL[(j - j0) * 3];
                float p0 = (q==0)?v0:(q==1)?v3:(q==2)?v6:v9;
                float p1 = (q==0)?v1:(q==1)?v4:(q==2)?v7:v10;
                float p2 = (q==0)?v2:(q==1)?v5:(q==2)?v8:v11;
                float d = fmaxf(fmaxf(fabsf(p0 - ce[0]), fabsf(p1 - ce[1])),
                                fabsf(p2 - ce[2]));
                im[q] = img;
                fg[q] = (d <= fs) ? 1 : 0;
            }
            iA = im[0]; cA = fg[0];
            #pragma unroll
            for (int q = 1; q < 4; q++) {
                if (im[q] == iA) cA += fg[q];
                else { iB = im[q]; cB += fg[q]; }         // at most 2 images
            }
        }
        unsigned long long am = __ballot(act);
        if (am == ~0ull) {                                // full wave active
            int first = __shfl(iA, 0);
            int lastA = __shfl(iA, 63), lastB = __shfl(iB, 63);
            int last  = (lastB >= 0) ? lastB : lastA;
            if (last - first <= 1) {                      // wave spans <=2 imgs
                int tot  = cA + cB;
                int low  = ((iA == first) ? cA : 0) + ((iB == first) ? cB : 0);
                int high = tot - low;
                #pragma unroll
                for (int mm = 32; mm >= 1; mm >>= 1) {
                    low  += __shfl_xor(low, mm);
                    high += __shfl_xor(high, mm);
                }
                if ((tid & 63) == 0) {
                    atomicAdd(&cntL[first - imgBase], low);
                    if (high > 0) atomicAdd(&cntL[first + 1 - imgBase], high);
                }
                continue;
            }
        }
        if (iA >= 0) atomicAdd(&cntL[iA - imgBase], cA);
        if (iB >= 0) atomicAdd(&cntL[iB - imgBase], cB);
    }
    __syncthreads();

    for (int t = tid; t < nImg; t += THREADS) {
        int img = imgBase + t;
        int lo = img * s2, hi = lo + s2;
        int g = sc * IMGS_PER_SCALE + img;
        int v = cntL[t];
        if (lo >= P0 && hi <= Pend) wsCounts[g] = v;      // image fully mine
        else atomicAdd(&wsCounts[g], v);                  // boundary image
    }
}

// ---------------------------------------------------------------------------
// Kernel 2: classify + CC for partial images.
// 500 blocks x 64 images. Fast paths are analytic; slow path: wave-parallel
// shuffle CC for s<=7 (s^2<=64), block LDS CC for s>=9 (vanishingly rare).
// ---------------------------------------------------------------------------
__global__ __launch_bounds__(THREADS)
void cc_kernel(Ptrs ptrs, const int* __restrict__ wsCounts,
               int* __restrict__ wsNcomp, int* __restrict__ wsMaxc)
{
    const int bid = blockIdx.x;                 // 25 blocks per scale
    const int sc  = bid / 25;
    const int s   = 3 + 2 * sc;
    const int s2  = s * s;
    const int BIGL = s2 + 1;
    const float* __restrict__ x = ptrs.p[sc];
    const int imgLoc0 = (bid % 25) * 64;
    const int tid = threadIdx.x;
    const unsigned mS = 0xFFFFFFFFu / (unsigned)s + 1;

    __shared__ int slowList[64];
    __shared__ int nslow;
    __shared__ int lab[S2MAX];
    __shared__ int szh[S2MAX];
    __shared__ int redN[4], redM[4];

    if (tid == 0) nslow = 0;
    __syncthreads();
    if (tid < 64) {
        int img = imgLoc0 + tid;
        int g = sc * IMGS_PER_SCALE + img;
        int c = wsCounts[g];
        if (c == s2)      { wsNcomp[g] = 1; wsMaxc[g] = s2; }
        else if (c == 0)  { wsNcomp[g] = 0; wsMaxc[g] = 0; }
        else { int k = atomicAdd(&nslow, 1); slowList[k] = img; }
    }
    __syncthreads();
    const int ns = nslow;
    if (ns == 0) return;

    if (s2 <= 64) {
        // ---- per-wave shuffle CC, one image per wave iteration ----
        const int w = tid >> 6, l = tid & 63;
        for (int idx = w; idx < ns; idx += 4) {
            int img = slowList[idx];
            int fg = 0, labr = BIGL, i1 = 0, i2 = 0;
            if (l < s2) {
                i1 = (int)__umulhi((unsigned)l, mS);
                i2 = l - i1 * s;
                int M = img * s + i1;
                int j = M / PATCH;
                const float* ce = x + (size_t)(((j * PATCH + 49) * s + (s >> 1)) * 3);
                const float* px = x + ((size_t)img * s2 + l) * 3;
                float d = fmaxf(fmaxf(fabsf(px[0] - ce[0]), fabsf(px[1] - ce[1])),
                                fabsf(px[2] - ce[2]));
                if (d <= (float)s) { fg = 1; labr = l + 1; }
            }
            for (;;) {
                int m = labr;
                int vU = __shfl(labr, (l - s) & 63);
                int vD = __shfl(labr, (l + s) & 63);
                int vL = __shfl(labr, (l - 1) & 63);
                int vR = __shfl(labr, (l + 1) & 63);
                if (fg) {
                    if (i1 > 0)     m = min(m, vU);
                    if (i1 < s - 1) m = min(m, vD);
                    if (i2 > 0)     m = min(m, vL);
                    if (i2 < s - 1) m = min(m, vR);
                }
                int vJ = __shfl(labr, (m - 1) & 63);      // pointer jump
                if (fg) m = min(m, vJ);
                unsigned long long chg = __ballot(m < labr);
                labr = m;
                if (chg == 0) break;
            }
            int ncomp = __popcll(__ballot(fg && labr == l + 1));
            int mc = 0;
            for (int r = 0; r < s2; r++) {
                int szr = __popcll(__ballot(fg && labr == r + 1));
                mc = max(mc, szr);
            }
            if (l == 0) {
                int g = sc * IMGS_PER_SCALE + img;
                wsNcomp[g] = ncomp; wsMaxc[g] = mc;
            }
        }
    } else {
        // ---- block-sequential LDS CC (needs a bg pixel at s>=9: ~never) ----
        for (int idx = 0; idx < ns; idx++) {
            int img = slowList[idx];
            const int ibase = img * s2 * 3;
            for (int i = tid; i < s2; i += THREADS) {
                int i1 = (int)__umulhi((unsigned)i, mS);
                int M = img * s + i1;
                int j = M / PATCH;
                const float* ce = x + (size_t)(((j * PATCH + 49) * s + (s >> 1)) * 3);
                const float* px = x + ibase + i * 3;
                float d = fmaxf(fmaxf(fabsf(px[0] - ce[0]), fabsf(px[1] - ce[1])),
                                fabsf(px[2] - ce[2]));
                lab[i] = (d <= (float)s) ? (i + 1) : BIGL;
                szh[i] = 0;
            }
            __syncthreads();
            for (;;) {
                bool changed = false;
                for (int i = tid; i < s2; i += THREADS) {
                    int L0 = lab[i];
                    if (L0 <= s2) {
                        int i1 = (int)__umulhi((unsigned)i, mS);
                        int i2 = i - i1 * s;
                        int m = L0;
                        if (i1 > 0)     m = min(m, lab[i - s]);
                        if (i1 < s - 1) m = min(m, lab[i + s]);
                        if (i2 > 0)     m = min(m, lab[i - 1]);
                        if (i2 < s - 1) m = min(m, lab[i + 1]);
                        m = min(m, lab[m - 1]);
                        if (m < L0) { lab[i] = m; changed = true; }
                    }
                }
                if (__syncthreads_count(changed ? 1 : 0) == 0) break;
            }
            int ncomp = 0;
            for (int i = tid; i < s2; i += THREADS) {
                int L = lab[i];
                if (L <= s2) {
                    atomicAdd(&szh[L - 1], 1);
                    if (L == i + 1) ncomp++;
                }
            }
            __syncthreads();
            int mc = 0;
            for (int i = tid; i < s2; i += THREADS) mc = max(mc, szh[i]);
            for (int m = 32; m >= 1; m >>= 1) {
                ncomp += __shfl_xor(ncomp, m);
                mc     = max(mc, __shfl_xor(mc, m));
            }
            int wid = tid >> 6, lane = tid & 63;
            if (lane == 0) { redN[wid] = ncomp; redM[wid] = mc; }
            __syncthreads();
            if (tid == 0) {
                int g = sc * IMGS_PER_SCALE + img;
                wsNcomp[g] = redN[0] + redN[1] + redN[2] + redN[3];
                wsMaxc[g]  = max(max(redM[0], redM[1]), max(redM[2], redM[3]));
            }
            __syncthreads();
        }
    }
}

// ---------------------------------------------------------------------------
// Kernel 3: per-scale finalization (unchanged, verified).
// ---------------------------------------------------------------------------
__global__ __launch_bounds__(THREADS)
void final_kernel(const int* __restrict__ wsCounts,
                  const int* __restrict__ wsNcomp,
                  const int* __restrict__ wsMaxc,
                  float* __restrict__ out)
{
    const int scale = blockIdx.x;
    const int s  = 3 + 2 * scale;
    const int s2 = s * s;
    const int tid = threadIdx.x;
    const int NB = IMGS_PER_SCALE;
    const int CH = 7;

    __shared__ int nc[IMGS_PER_SCALE];
    __shared__ int tsum[THREADS];

    for (int i = tid; i < NB; i += THREADS) nc[i] = wsNcomp[scale * NB + i];
    __syncthreads();

    int lsum = 0;
    for (int k = 0; k < CH; k++) {
        int idx = tid * CH + k;
        if (idx < NB) lsum += nc[idx];
    }
    tsum[tid] = lsum;
    __syncthreads();
    for (int st = 1; st < THREADS; st <<= 1) {
        int v = (tid >= st) ? tsum[tid - st] : 0;
        __syncthreads();
        tsum[tid] += v;
        __syncthreads();
    }
    int run = (tid > 0) ? tsum[tid - 1] : 0;
    for (int k = 0; k < CH; k++) {
        int idx = tid * CH + k;
        if (idx < NB) {
            int v = nc[idx];
            run += v;
            nc[idx] = (v > 0) ? run : 0;
        }
    }
    __syncthreads();

    int b    = tid >> 4;
    int lane = tid & 15;
    float fdsum = 0.f, sn = 0.f, sn2 = 0.f, pcsum = 0.f;
    int pqc = 0, bg = 0, mcx = 0;
    for (int q = lane; q < PATCH; q += 16) {
        int i = b * PATCH + q;
        int c = wsCounts[scale * NB + i];
        float n = (c > 0) ? (float)c : 1.0f;
        fdsum += 1.0f / n;
        sn    += n;
        sn2   += n * n;
        pqc   += ((float)c / (float)s2 >= 0.59275f) ? 1 : 0;
        bg    += (s2 - c);
        mcx    = max(mcx, wsMaxc[scale * NB + i]);
        pcsum += (float)nc[i];
    }
    for (int m = 8; m >= 1; m >>= 1) {
        fdsum += __shfl_xor(fdsum, m);
        sn    += __shfl_xor(sn, m);
        sn2   += __shfl_xor(sn2, m);
        pcsum += __shfl_xor(pcsum, m);
        pqc   += __shfl_xor(pqc, m);
        bg    += __shfl_xor(bg, m);
        mcx    = max(mcx, __shfl_xor(mcx, m));
    }
    if (lane == 0) {
        float fd  = fdsum / 100.0f;
        float m1  = sn / 100.0f;
        float mu1 = m1 * m1;
        float mu2 = sn2 / 100.0f;
        float lac = (mu2 - mu1) / mu1;
        float pq  = (float)pqc / 100.0f;
        float pc  = pcsum / 100.0f;
        float pm  = (float)max(bg, mcx);
        out[b * 100 +  0 + scale] = pc;
        out[b * 100 + 20 + scale] = pq;
        out[b * 100 + 40 + scale] = pm;
        out[b * 100 + 60 + scale] = lac;
        out[b * 100 + 80 + scale] = fd;
    }
}

extern "C" void kernel_launch(void* const* d_in, const int* in_sizes, int n_in,
                              void* d_out, int out_size, void* d_ws, size_t ws_size,
                              hipStream_t stream)
{
    Ptrs ptrs;
    for (int i = 0; i < NSCALES; i++) ptrs.p[i] = (const float*)d_in[i];

    Starts st;
    int acc = 0;
    for (int i = 0; i < NSCALES; i++) {
        st.blkStart[i] = acc;
        int s = 3 + 2 * i, s2 = s * s;
        acc += (IMGS_PER_SCALE * s2 + CHUNKPX - 1) / CHUNKPX;
    }

    int* wsC = (int*)d_ws;
    int* wsN = wsC + TOTAL_IMGS;
    int* wsM = wsN + TOTAL_IMGS;

    hipMemsetAsync(wsC, 0, TOTAL_IMGS * sizeof(int), stream);
    count_kernel<<<acc, THREADS, 0, stream>>>(ptrs, st, wsC);
    cc_kernel<<<TOTAL_IMGS / 64, THREADS, 0, stream>>>(ptrs, wsC, wsN, wsM);
    final_kernel<<<NSCALES, THREADS, 0, stream>>>(wsC, wsN, wsM, (float*)d_out);
}

// Round 4
// 67.681 us; speedup vs baseline: 1.0941x; 1.0941x over previous
//
#include <hip/hip_runtime.h>

#define NSCALES 20
#define PATCH 100
#define IMGS_PER_SCALE 1600
#define TOTAL_IMGS 32000
#define THREADS 256
#define PXT 16                          // pixels per thread
#define CHUNKPX (THREADS * PXT)         // 4096 pixels per block
#define MAXIMG 464                      // >= ceil(4096/9)+1
#define S2MAX 1681

struct Ptrs   { const float* p[NSCALES]; };
struct Starts { int blkStart[NSCALES]; };

// ---------------------------------------------------------------------------
// Kernel 1 body (templated on S): streaming per-image fg counts.
// Thread t owns 16 contiguous pixels; 12 independent float4 loads in flight;
// constant-divisor index math; <=3 LDS atomics per thread, once.
// Output: two partial-count slots per image (an image spans <=2 blocks).
// ---------------------------------------------------------------------------
template<int S>
__device__ __forceinline__ void count_body(const float* __restrict__ x,
                                           int blkLocal, int sc,
                                           int* __restrict__ wsC2,
                                           float4* cenL, int* cntL)
{
    constexpr int S2 = S * S;
    constexpr int ROWDIV = 100 * S;     // j = P / (100*S)  (nested floor ok)
    const int Ntot = IMGS_PER_SCALE * S2;
    const int P0   = blkLocal * CHUNKPX;
    const int Pend = min(P0 + CHUNKPX, Ntot);
    const int tid  = threadIdx.x;

    const int imgBase = P0 / S2;
    const int imgLast = (Pend - 1) / S2;
    const int nImg    = imgLast - imgBase + 1;            // <= 457
    const int j0      = P0 / ROWDIV;
    const int jEnd    = (Pend - 1) / ROWDIV;
    const int nj      = jEnd - j0 + 1;                    // <= 15

    if (tid < nj) {
        int j = j0 + tid;
        const float* c = x + (size_t)(((j * PATCH + 49) * S + (S >> 1)) * 3);
        cenL[tid] = make_float4(c[0], c[1], c[2], 0.f);
    }
    for (int t = tid; t < nImg; t += THREADS) cntL[t] = 0;
    __syncthreads();

    const int p0 = P0 + tid * PXT;
    if (p0 < Pend) {                                      // Ntot % 16 == 0
        // ---- 12 independent 16B loads (192B contiguous per thread) ----
        const float4* q4 = (const float4*)(x + (size_t)p0 * 3);
        float4 v[12];
        #pragma unroll
        for (int q = 0; q < 12; q++) v[q] = q4[q];
        const float* f = (const float*)v;

        const int iA = p0 / S2;                           // const divide
        const int r0 = p0 - iA * S2;                      // pos in image A
        const int jA = p0 / ROWDIV;
        const int jB = (p0 + PXT - 1) / ROWDIV;
        const float4 ceA = cenL[jA - j0];
        const float4 ceB = (jB != jA) ? cenL[jB - j0] : ceA;
        const int flip = (jB != jA) ? ((jA + 1) * ROWDIV - p0) : PXT;

        int cA = 0, cB = 0, cC = 0;
        #pragma unroll
        for (int q = 0; q < PXT; q++) {
            const float4 ce = (q < flip) ? ceA : ceB;
            float d = fmaxf(fmaxf(fabsf(f[q*3+0] - ce.x),
                                  fabsf(f[q*3+1] - ce.y)),
                            fabsf(f[q*3+2] - ce.z));
            int fg = (d <= (float)S) ? 1 : 0;
            int t  = r0 + q;                              // offset from img A
            if constexpr (S2 >= PXT) {                    // spans <= 2 images
                cA += (t < S2) ? fg : 0;
                cB += (t >= S2) ? fg : 0;
            } else {                                      // S==3: <= 3 images
                cA += (t < S2) ? fg : 0;
                cB += (t >= S2 && t < 2 * S2) ? fg : 0;
                cC += (t >= 2 * S2) ? fg : 0;
            }
        }
        atomicAdd(&cntL[iA - imgBase], cA);
        if (cB) atomicAdd(&cntL[iA + 1 - imgBase], cB);
        if constexpr (S2 < PXT) {
            if (cC) atomicAdd(&cntL[iA + 2 - imgBase], cC);
        }
    }
    __syncthreads();

    // ---- deterministic two-slot writeback (no global atomics) ----
    for (int t = tid; t < nImg; t += THREADS) {
        int img = imgBase + t;
        int lo = img * S2, hi = lo + S2;
        int g = sc * IMGS_PER_SCALE + img;
        int vv = cntL[t];
        if (lo >= P0) {                                   // I own the start
            wsC2[2 * g] = vv;
            if (hi <= Pend) wsC2[2 * g + 1] = 0;          // fully mine
        } else {
            wsC2[2 * g + 1] = vv;                         // continuation
        }
    }
}

__global__ __launch_bounds__(THREADS)
void count_kernel(Ptrs ptrs, Starts st, int* __restrict__ wsC2)
{
    const int bid = blockIdx.x;
    int sc = 0;
    #pragma unroll
    for (int k = 1; k < NSCALES; k++) sc += (bid >= st.blkStart[k]) ? 1 : 0;
    const int blkLocal = bid - st.blkStart[sc];

    __shared__ float4 cenL[16];
    __shared__ int    cntL[MAXIMG];

    switch (sc) {
#define CASE(i) case i: count_body<3 + 2*(i)>(ptrs.p[i], blkLocal, i, wsC2, cenL, cntL); break;
        CASE(0)  CASE(1)  CASE(2)  CASE(3)  CASE(4)
        CASE(5)  CASE(6)  CASE(7)  CASE(8)  CASE(9)
        CASE(10) CASE(11) CASE(12) CASE(13) CASE(14)
        CASE(15) CASE(16) CASE(17) CASE(18) CASE(19)
#undef CASE
    }
}

// ---------------------------------------------------------------------------
// Kernel 2: classify + CC for partial images. 500 blocks x 64 images.
// Also combines the two count slots -> wsCnt for the final kernel.
// ---------------------------------------------------------------------------
__global__ __launch_bounds__(THREADS)
void cc_kernel(Ptrs ptrs, const int* __restrict__ wsC2,
               int* __restrict__ wsCnt,
               int* __restrict__ wsNcomp, int* __restrict__ wsMaxc)
{
    const int bid = blockIdx.x;                 // 25 blocks per scale
    const int sc  = bid / 25;
    const int s   = 3 + 2 * sc;
    const int s2  = s * s;
    const int BIGL = s2 + 1;
    const float* __restrict__ x = ptrs.p[sc];
    const int imgLoc0 = (bid % 25) * 64;
    const int tid = threadIdx.x;
    const unsigned mS = 0xFFFFFFFFu / (unsigned)s + 1;

    __shared__ int slowList[64];
    __shared__ int nslow;
    __shared__ int lab[S2MAX];
    __shared__ int szh[S2MAX];
    __shared__ int redN[4], redM[4];

    if (tid == 0) nslow = 0;
    __syncthreads();
    if (tid < 64) {
        int img = imgLoc0 + tid;
        int g = sc * IMGS_PER_SCALE + img;
        int c = wsC2[2 * g] + wsC2[2 * g + 1];
        wsCnt[g] = c;
        if (c == s2)      { wsNcomp[g] = 1; wsMaxc[g] = s2; }
        else if (c == 0)  { wsNcomp[g] = 0; wsMaxc[g] = 0; }
        else { int k = atomicAdd(&nslow, 1); slowList[k] = img; }
    }
    __syncthreads();
    const int ns = nslow;
    if (ns == 0) return;

    if (s2 <= 64) {
        // ---- per-wave shuffle CC, one image per wave iteration ----
        const int w = tid >> 6, l = tid & 63;
        for (int idx = w; idx < ns; idx += 4) {
            int img = slowList[idx];
            int fg = 0, labr = BIGL, i1 = 0, i2 = 0;
            if (l < s2) {
                i1 = (int)__umulhi((unsigned)l, mS);
                i2 = l - i1 * s;
                int M = img * s + i1;
                int j = M / PATCH;
                const float* ce = x + (size_t)(((j * PATCH + 49) * s + (s >> 1)) * 3);
                const float* px = x + ((size_t)img * s2 + l) * 3;
                float d = fmaxf(fmaxf(fabsf(px[0] - ce[0]), fabsf(px[1] - ce[1])),
                                fabsf(px[2] - ce[2]));
                if (d <= (float)s) { fg = 1; labr = l + 1; }
            }
            for (;;) {
                int m = labr;
                int vU = __shfl(labr, (l - s) & 63);
                int vD = __shfl(labr, (l + s) & 63);
                int vL = __shfl(labr, (l - 1) & 63);
                int vR = __shfl(labr, (l + 1) & 63);
                if (fg) {
                    if (i1 > 0)     m = min(m, vU);
                    if (i1 < s - 1) m = min(m, vD);
                    if (i2 > 0)     m = min(m, vL);
                    if (i2 < s - 1) m = min(m, vR);
                }
                int vJ = __shfl(labr, (m - 1) & 63);      // pointer jump
                if (fg) m = min(m, vJ);
                unsigned long long chg = __ballot(m < labr);
                labr = m;
                if (chg == 0) break;
            }
            int ncomp = __popcll(__ballot(fg && labr == l + 1));
            int mc = 0;
            for (int r = 0; r < s2; r++) {
                int szr = __popcll(__ballot(fg && labr == r + 1));
                mc = max(mc, szr);
            }
            if (l == 0) {
                int g = sc * IMGS_PER_SCALE + img;
                wsNcomp[g] = ncomp; wsMaxc[g] = mc;
            }
        }
    } else {
        // ---- block-sequential LDS CC (bg pixel at s>=9: vanishingly rare) --
        for (int idx = 0; idx < ns; idx++) {
            int img = slowList[idx];
            const int ibase = img * s2 * 3;
            for (int i = tid; i < s2; i += THREADS) {
                int i1 = (int)__umulhi((unsigned)i, mS);
                int M = img * s + i1;
                int j = M / PATCH;
                const float* ce = x + (size_t)(((j * PATCH + 49) * s + (s >> 1)) * 3);
                const float* px = x + ibase + i * 3;
                float d = fmaxf(fmaxf(fabsf(px[0] - ce[0]), fabsf(px[1] - ce[1])),
                                fabsf(px[2] - ce[2]));
                lab[i] = (d <= (float)s) ? (i + 1) : BIGL;
                szh[i] = 0;
            }
            __syncthreads();
            for (;;) {
                bool changed = false;
                for (int i = tid; i < s2; i += THREADS) {
                    int L0 = lab[i];
                    if (L0 <= s2) {
                        int i1 = (int)__umulhi((unsigned)i, mS);
                        int i2 = i - i1 * s;
                        int m = L0;
                        if (i1 > 0)     m = min(m, lab[i - s]);
                        if (i1 < s - 1) m = min(m, lab[i + s]);
                        if (i2 > 0)     m = min(m, lab[i - 1]);
                        if (i2 < s - 1) m = min(m, lab[i + 1]);
                        m = min(m, lab[m - 1]);
                        if (m < L0) { lab[i] = m; changed = true; }
                    }
                }
                if (__syncthreads_count(changed ? 1 : 0) == 0) break;
            }
            int ncomp = 0;
            for (int i = tid; i < s2; i += THREADS) {
                int L = lab[i];
                if (L <= s2) {
                    atomicAdd(&szh[L - 1], 1);
                    if (L == i + 1) ncomp++;
                }
            }
            __syncthreads();
            int mc = 0;
            for (int i = tid; i < s2; i += THREADS) mc = max(mc, szh[i]);
            for (int m = 32; m >= 1; m >>= 1) {
                ncomp += __shfl_xor(ncomp, m);
                mc     = max(mc, __shfl_xor(mc, m));
            }
            int wid = tid >> 6, lane = tid & 63;
            if (lane == 0) { redN[wid] = ncomp; redM[wid] = mc; }
            __syncthreads();
            if (tid == 0) {
                int g = sc * IMGS_PER_SCALE + img;
                wsNcomp[g] = redN[0] + redN[1] + redN[2] + redN[3];
                wsMaxc[g]  = max(max(redM[0], redM[1]), max(redM[2], redM[3]));
            }
            __syncthreads();
        }
    }
}

// ---------------------------------------------------------------------------
// Kernel 3: per-scale finalization (verified).
// ---------------------------------------------------------------------------
__global__ __launch_bounds__(THREADS)
void final_kernel(const int* __restrict__ wsCnt,
                  const int* __restrict__ wsNcomp,
                  const int* __restrict__ wsMaxc,
                  float* __restrict__ out)
{
    const int scale = blockIdx.x;
    const int s  = 3 + 2 * scale;
    const int s2 = s * s;
    const int tid = threadIdx.x;
    const int NB = IMGS_PER_SCALE;
    const int CH = 7;

    __shared__ int nc[IMGS_PER_SCALE];
    __shared__ int tsum[THREADS];

    for (int i = tid; i < NB; i += THREADS) nc[i] = wsNcomp[scale * NB + i];
    __syncthreads();

    int lsum = 0;
    for (int k = 0; k < CH; k++) {
        int idx = tid * CH + k;
        if (idx < NB) lsum += nc[idx];
    }
    tsum[tid] = lsum;
    __syncthreads();
    for (int st = 1; st < THREADS; st <<= 1) {
        int v = (tid >= st) ? tsum[tid - st] : 0;
        __syncthreads();
        tsum[tid] += v;
        __syncthreads();
    }
    int run = (tid > 0) ? tsum[tid - 1] : 0;
    for (int k = 0; k < CH; k++) {
        int idx = tid * CH + k;
        if (idx < NB) {
            int v = nc[idx];
            run += v;
            nc[idx] = (v > 0) ? run : 0;
        }
    }
    __syncthreads();

    int b    = tid >> 4;
    int lane = tid & 15;
    float fdsum = 0.f, sn = 0.f, sn2 = 0.f, pcsum = 0.f;
    int pqc = 0, bg = 0, mcx = 0;
    for (int q = lane; q < PATCH; q += 16) {
        int i = b * PATCH + q;
        int c = wsCnt[scale * NB + i];
        float n = (c > 0) ? (float)c : 1.0f;
        fdsum += 1.0f / n;
        sn    += n;
        sn2   += n * n;
        pqc   += ((float)c / (float)s2 >= 0.59275f) ? 1 : 0;
        bg    += (s2 - c);
        mcx    = max(mcx, wsMaxc[scale * NB + i]);
        pcsum += (float)nc[i];
    }
    for (int m = 8; m >= 1; m >>= 1) {
        fdsum += __shfl_xor(fdsum, m);
        sn    += __shfl_xor(sn, m);
        sn2   += __shfl_xor(sn2, m);
        pcsum += __shfl_xor(pcsum, m);
        pqc   += __shfl_xor(pqc, m);
        bg    += __shfl_xor(bg, m);
        mcx    = max(mcx, __shfl_xor(mcx, m));
    }
    if (lane == 0) {
        float fd  = fdsum / 100.0f;
        float m1  = sn / 100.0f;
        float mu1 = m1 * m1;
        float mu2 = sn2 / 100.0f;
        float lac = (mu2 - mu1) / mu1;
        float pq  = (float)pqc / 100.0f;
        float pc  = pcsum / 100.0f;
        float pm  = (float)max(bg, mcx);
        out[b * 100 +  0 + scale] = pc;
        out[b * 100 + 20 + scale] = pq;
        out[b * 100 + 40 + scale] = pm;
        out[b * 100 + 60 + scale] = lac;
        out[b * 100 + 80 + scale] = fd;
    }
}

extern "C" void kernel_launch(void* const* d_in, const int* in_sizes, int n_in,
                              void* d_out, int out_size, void* d_ws, size_t ws_size,
                              hipStream_t stream)
{
    Ptrs ptrs;
    for (int i = 0; i < NSCALES; i++) ptrs.p[i] = (const float*)d_in[i];

    Starts st;
    int acc = 0;
    for (int i = 0; i < NSCALES; i++) {
        st.blkStart[i] = acc;
        int s = 3 + 2 * i, s2 = s * s;
        acc += (IMGS_PER_SCALE * s2 + CHUNKPX - 1) / CHUNKPX;
    }

    int* wsC2  = (int*)d_ws;                    // 2 slots per image
    int* wsCnt = wsC2 + 2 * TOTAL_IMGS;
    int* wsN   = wsCnt + TOTAL_IMGS;
    int* wsM   = wsN + TOTAL_IMGS;

    count_kernel<<<acc, THREADS, 0, stream>>>(ptrs, st, wsC2);
    cc_kernel<<<TOTAL_IMGS / 64, THREADS, 0, stream>>>(ptrs, wsC2, wsCnt, wsN, wsM);
    final_kernel<<<NSCALES, THREADS, 0, stream>>>(wsCnt, wsN, wsM, (float*)d_out);
}

// Round 5
// 67.629 us; speedup vs baseline: 1.0949x; 1.0008x over previous
//
#include <hip/hip_runtime.h>

#define NSCALES 20
#define PATCH 100
#define IMGS_PER_SCALE 1600
#define TOTAL_IMGS 32000
#define THREADS 256
#define CHUNKPX 2048                    // pixels per block (>= 41*41=1681)
#define NF4BLK (CHUNKPX * 3 / 4)        // 1536 float4 per chunk
#define F4PT (NF4BLK / THREADS)         // 6 float4 per thread staged
#define MAXIMG 240                      // >= ceil(2048/9)+1 = 229
#define S2MAX 1681

struct Ptrs   { const float* p[NSCALES]; };
struct Starts { int blkStart[NSCALES]; };

// ---------------------------------------------------------------------------
// Kernel 1 (templated on S): streaming per-image fg counts, LDS-staged.
// Stage: 6 coalesced float4 loads/thread (1KB/wave-instr), LDS write
// conflict-free. Read-back: 2 groups x 3 ds_read_b128 at stride 48B --
// bank-uniform (12i mod 32 tiles all banks). <=4 LDS atomics/thread.
// Output: two partial-count slots per image (image spans <=2 blocks).
// ---------------------------------------------------------------------------
template<int S>
__device__ __forceinline__ void count_body(const float* __restrict__ x,
                                           int blkLocal, int sc,
                                           int* __restrict__ wsC2,
                                           float4* stgF4, float4* cenL,
                                           int* cntL)
{
    constexpr int S2 = S * S;
    constexpr int ROWDIV = 100 * S;     // j = P / (100*S)
    const int Ntot   = IMGS_PER_SCALE * S2;       // multiple of 16
    const int NF4tot = Ntot * 3 / 4;
    const int P0     = blkLocal * CHUNKPX;
    const int Pend   = min(P0 + CHUNKPX, Ntot);
    const int tid    = threadIdx.x;

    const int imgBase = P0 / S2;
    const int imgLast = (Pend - 1) / S2;
    const int nImg    = imgLast - imgBase + 1;    // <= 229
    const int j0      = P0 / ROWDIV;
    const int jEnd    = (Pend - 1) / ROWDIV;
    const int nj      = jEnd - j0 + 1;            // <= 8

    // ---- coalesced staging: issue all 6 loads, then write LDS ----
    const float4* __restrict__ x4 = (const float4*)x;
    const int F0 = blkLocal * NF4BLK;
    float4 stg[F4PT];
    #pragma unroll
    for (int it = 0; it < F4PT; it++) {
        int fi = F0 + it * THREADS + tid;
        stg[it] = x4[min(fi, NF4tot - 1)];        // clamp: last block partial
    }
    if (tid < nj) {
        int j = j0 + tid;
        const float* c = x + (size_t)(((j * PATCH + 49) * S + (S >> 1)) * 3);
        cenL[tid] = make_float4(c[0], c[1], c[2], 0.f);
    }
    for (int t = tid; t < nImg; t += THREADS) cntL[t] = 0;
    #pragma unroll
    for (int it = 0; it < F4PT; it++) stgF4[it * THREADS + tid] = stg[it];
    __syncthreads();

    // ---- per-thread: two 4-pixel groups, stride 48B (bank-uniform) ----
    const float* lf = (const float*)stgF4;
    #pragma unroll
    for (int half = 0; half < 2; half++) {
        const int p0 = P0 + half * (CHUNKPX / 2) + tid * 4;
        if (p0 < Pend) {                          // p0+3 < Pend too (mult of 4)
            const float4* src = (const float4*)(lf + (size_t)(p0 - P0) * 3);
            float4 a = src[0], b = src[1], c = src[2];
            const float f[12] = {a.x,a.y,a.z,a.w, b.x,b.y,b.z,b.w,
                                 c.x,c.y,c.z,c.w};
            const int iA = p0 / S2;               // constant divides
            const int r0 = p0 - iA * S2;
            const int jA = p0 / ROWDIV;
            const int jB = (p0 + 3) / ROWDIV;
            const float4 ceA = cenL[jA - j0];
            const float4 ceB = (jB != jA) ? cenL[jB - j0] : ceA;
            const int flip = (jB != jA) ? ((jA + 1) * ROWDIV - p0) : 4;

            int cA = 0, cB = 0;
            #pragma unroll
            for (int q = 0; q < 4; q++) {         // 4px spans <=2 images
                const float4 ce = (q < flip) ? ceA : ceB;
                float d = fmaxf(fmaxf(fabsf(f[q*3+0] - ce.x),
                                      fabsf(f[q*3+1] - ce.y)),
                                fabsf(f[q*3+2] - ce.z));
                int fg = (d <= (float)S) ? 1 : 0;
                int t  = r0 + q;
                cA += (t < S2) ? fg : 0;
                cB += (t >= S2) ? fg : 0;
            }
            atomicAdd(&cntL[iA - imgBase], cA);
            if (cB) atomicAdd(&cntL[iA + 1 - imgBase], cB);
        }
    }
    __syncthreads();

    // ---- deterministic two-slot writeback (no global atomics) ----
    for (int t = tid; t < nImg; t += THREADS) {
        int img = imgBase + t;
        int lo = img * S2, hi = lo + S2;
        int g = sc * IMGS_PER_SCALE + img;
        int vv = cntL[t];
        if (lo >= P0) {                           // I own the image start
            wsC2[2 * g] = vv;
            if (hi <= Pend) wsC2[2 * g + 1] = 0;  // fully mine
        } else {
            wsC2[2 * g + 1] = vv;                 // continuation
        }
    }
}

__global__ __launch_bounds__(THREADS)
void count_kernel(Ptrs ptrs, Starts st, int* __restrict__ wsC2)
{
    const int bid = blockIdx.x;
    int sc = 0;
    #pragma unroll
    for (int k = 1; k < NSCALES; k++) sc += (bid >= st.blkStart[k]) ? 1 : 0;
    const int blkLocal = bid - st.blkStart[sc];

    __shared__ float4 stgF4[NF4BLK];
    __shared__ float4 cenL[8];
    __shared__ int    cntL[MAXIMG];

    switch (sc) {
#define CASE(i) case i: count_body<3 + 2*(i)>(ptrs.p[i], blkLocal, i, wsC2, stgF4, cenL, cntL); break;
        CASE(0)  CASE(1)  CASE(2)  CASE(3)  CASE(4)
        CASE(5)  CASE(6)  CASE(7)  CASE(8)  CASE(9)
        CASE(10) CASE(11) CASE(12) CASE(13) CASE(14)
        CASE(15) CASE(16) CASE(17) CASE(18) CASE(19)
#undef CASE
    }
}

// ---------------------------------------------------------------------------
// Kernel 2: classify + CC for partial images. 500 blocks x 64 images.
// Combines the two count slots -> wsCnt. Analytic fast paths; wave-shuffle
// CC for s<=7; block LDS CC for s>=9 (vanishingly rare).
// ---------------------------------------------------------------------------
__global__ __launch_bounds__(THREADS)
void cc_kernel(Ptrs ptrs, const int* __restrict__ wsC2,
               int* __restrict__ wsCnt,
               int* __restrict__ wsNcomp, int* __restrict__ wsMaxc)
{
    const int bid = blockIdx.x;                 // 25 blocks per scale
    const int sc  = bid / 25;
    const int s   = 3 + 2 * sc;
    const int s2  = s * s;
    const int BIGL = s2 + 1;
    const float* __restrict__ x = ptrs.p[sc];
    const int imgLoc0 = (bid % 25) * 64;
    const int tid = threadIdx.x;
    const unsigned mS = 0xFFFFFFFFu / (unsigned)s + 1;

    __shared__ int slowList[64];
    __shared__ int nslow;
    __shared__ int lab[S2MAX];
    __shared__ int szh[S2MAX];
    __shared__ int redN[4], redM[4];

    if (tid == 0) nslow = 0;
    __syncthreads();
    if (tid < 64) {
        int img = imgLoc0 + tid;
        int g = sc * IMGS_PER_SCALE + img;
        int c = wsC2[2 * g] + wsC2[2 * g + 1];
        wsCnt[g] = c;
        if (c == s2)      { wsNcomp[g] = 1; wsMaxc[g] = s2; }
        else if (c == 0)  { wsNcomp[g] = 0; wsMaxc[g] = 0; }
        else { int k = atomicAdd(&nslow, 1); slowList[k] = img; }
    }
    __syncthreads();
    const int ns = nslow;
    if (ns == 0) return;

    if (s2 <= 64) {
        // ---- per-wave shuffle CC, one image per wave iteration ----
        const int w = tid >> 6, l = tid & 63;
        for (int idx = w; idx < ns; idx += 4) {
            int img = slowList[idx];
            int fg = 0, labr = BIGL, i1 = 0, i2 = 0;
            if (l < s2) {
                i1 = (int)__umulhi((unsigned)l, mS);
                i2 = l - i1 * s;
                int M = img * s + i1;
                int j = M / PATCH;
                const float* ce = x + (size_t)(((j * PATCH + 49) * s + (s >> 1)) * 3);
                const float* px = x + ((size_t)img * s2 + l) * 3;
                float d = fmaxf(fmaxf(fabsf(px[0] - ce[0]), fabsf(px[1] - ce[1])),
                                fabsf(px[2] - ce[2]));
                if (d <= (float)s) { fg = 1; labr = l + 1; }
            }
            for (;;) {
                int m = labr;
                int vU = __shfl(labr, (l - s) & 63);
                int vD = __shfl(labr, (l + s) & 63);
                int vL = __shfl(labr, (l - 1) & 63);
                int vR = __shfl(labr, (l + 1) & 63);
                if (fg) {
                    if (i1 > 0)     m = min(m, vU);
                    if (i1 < s - 1) m = min(m, vD);
                    if (i2 > 0)     m = min(m, vL);
                    if (i2 < s - 1) m = min(m, vR);
                }
                int vJ = __shfl(labr, (m - 1) & 63);      // pointer jump
                if (fg) m = min(m, vJ);
                unsigned long long chg = __ballot(m < labr);
                labr = m;
                if (chg == 0) break;
            }
            int ncomp = __popcll(__ballot(fg && labr == l + 1));
            int mc = 0;
            for (int r = 0; r < s2; r++) {
                int szr = __popcll(__ballot(fg && labr == r + 1));
                mc = max(mc, szr);
            }
            if (l == 0) {
                int g = sc * IMGS_PER_SCALE + img;
                wsNcomp[g] = ncomp; wsMaxc[g] = mc;
            }
        }
    } else {
        // ---- block-sequential LDS CC (bg pixel at s>=9: vanishingly rare) --
        for (int idx = 0; idx < ns; idx++) {
            int img = slowList[idx];
            const int ibase = img * s2 * 3;
            for (int i = tid; i < s2; i += THREADS) {
                int i1 = (int)__umulhi((unsigned)i, mS);
                int M = img * s + i1;
                int j = M / PATCH;
                const float* ce = x + (size_t)(((j * PATCH + 49) * s + (s >> 1)) * 3);
                const float* px = x + ibase + i * 3;
                float d = fmaxf(fmaxf(fabsf(px[0] - ce[0]), fabsf(px[1] - ce[1])),
                                fabsf(px[2] - ce[2]));
                lab[i] = (d <= (float)s) ? (i + 1) : BIGL;
                szh[i] = 0;
            }
            __syncthreads();
            for (;;) {
                bool changed = false;
                for (int i = tid; i < s2; i += THREADS) {
                    int L0 = lab[i];
                    if (L0 <= s2) {
                        int i1 = (int)__umulhi((unsigned)i, mS);
                        int i2 = i - i1 * s;
                        int m = L0;
                        if (i1 > 0)     m = min(m, lab[i - s]);
                        if (i1 < s - 1) m = min(m, lab[i + s]);
                        if (i2 > 0)     m = min(m, lab[i - 1]);
                        if (i2 < s - 1) m = min(m, lab[i + 1]);
                        m = min(m, lab[m - 1]);
                        if (m < L0) { lab[i] = m; changed = true; }
                    }
                }
                if (__syncthreads_count(changed ? 1 : 0) == 0) break;
            }
            int ncomp = 0;
            for (int i = tid; i < s2; i += THREADS) {
                int L = lab[i];
                if (L <= s2) {
                    atomicAdd(&szh[L - 1], 1);
                    if (L == i + 1) ncomp++;
                }
            }
            __syncthreads();
            int mc = 0;
            for (int i = tid; i < s2; i += THREADS) mc = max(mc, szh[i]);
            for (int m = 32; m >= 1; m >>= 1) {
                ncomp += __shfl_xor(ncomp, m);
                mc     = max(mc, __shfl_xor(mc, m));
            }
            int wid = tid >> 6, lane = tid & 63;
            if (lane == 0) { redN[wid] = ncomp; redM[wid] = mc; }
            __syncthreads();
            if (tid == 0) {
                int g = sc * IMGS_PER_SCALE + img;
                wsNcomp[g] = redN[0] + redN[1] + redN[2] + redN[3];
                wsMaxc[g]  = max(max(redM[0], redM[1]), max(redM[2], redM[3]));
            }
            __syncthreads();
        }
    }
}

// ---------------------------------------------------------------------------
// Kernel 3: per-scale finalization (verified).
// ---------------------------------------------------------------------------
__global__ __launch_bounds__(THREADS)
void final_kernel(const int* __restrict__ wsCnt,
                  const int* __restrict__ wsNcomp,
                  const int* __restrict__ wsMaxc,
                  float* __restrict__ out)
{
    const int scale = blockIdx.x;
    const int s  = 3 + 2 * scale;
    const int s2 = s * s;
    const int tid = threadIdx.x;
    const int NB = IMGS_PER_SCALE;
    const int CH = 7;

    __shared__ int nc[IMGS_PER_SCALE];
    __shared__ int tsum[THREADS];

    for (int i = tid; i < NB; i += THREADS) nc[i] = wsNcomp[scale * NB + i];
    __syncthreads();

    int lsum = 0;
    for (int k = 0; k < CH; k++) {
        int idx = tid * CH + k;
        if (idx < NB) lsum += nc[idx];
    }
    tsum[tid] = lsum;
    __syncthreads();
    for (int st = 1; st < THREADS; st <<= 1) {
        int v = (tid >= st) ? tsum[tid - st] : 0;
        __syncthreads();
        tsum[tid] += v;
        __syncthreads();
    }
    int run = (tid > 0) ? tsum[tid - 1] : 0;
    for (int k = 0; k < CH; k++) {
        int idx = tid * CH + k;
        if (idx < NB) {
            int v = nc[idx];
            run += v;
            nc[idx] = (v > 0) ? run : 0;
        }
    }
    __syncthreads();

    int b    = tid >> 4;
    int lane = tid & 15;
    float fdsum = 0.f, sn = 0.f, sn2 = 0.f, pcsum = 0.f;
    int pqc = 0, bg = 0, mcx = 0;
    for (int q = lane; q < PATCH; q += 16) {
        int i = b * PATCH + q;
        int c = wsCnt[scale * NB + i];
        float n = (c > 0) ? (float)c : 1.0f;
        fdsum += 1.0f / n;
        sn    += n;
        sn2   += n * n;
        pqc   += ((float)c / (float)s2 >= 0.59275f) ? 1 : 0;
        bg    += (s2 - c);
        mcx    = max(mcx, wsMaxc[scale * NB + i]);
        pcsum += (float)nc[i];
    }
    for (int m = 8; m >= 1; m >>= 1) {
        fdsum += __shfl_xor(fdsum, m);
        sn    += __shfl_xor(sn, m);
        sn2   += __shfl_xor(sn2, m);
        pcsum += __shfl_xor(pcsum, m);
        pqc   += __shfl_xor(pqc, m);
        bg    += __shfl_xor(bg, m);
        mcx    = max(mcx, __shfl_xor(mcx, m));
    }
    if (lane == 0) {
        float fd  = fdsum / 100.0f;
        float m1  = sn / 100.0f;
        float mu1 = m1 * m1;
        float mu2 = sn2 / 100.0f;
        float lac = (mu2 - mu1) / mu1;
        float pq  = (float)pqc / 100.0f;
        float pc  = pcsum / 100.0f;
        float pm  = (float)max(bg, mcx);
        out[b * 100 +  0 + scale] = pc;
        out[b * 100 + 20 + scale] = pq;
        out[b * 100 + 40 + scale] = pm;
        out[b * 100 + 60 + scale] = lac;
        out[b * 100 + 80 + scale] = fd;
    }
}

extern "C" void kernel_launch(void* const* d_in, const int* in_sizes, int n_in,
                              void* d_out, int out_size, void* d_ws, size_t ws_size,
                              hipStream_t stream)
{
    Ptrs ptrs;
    for (int i = 0; i < NSCALES; i++) ptrs.p[i] = (const float*)d_in[i];

    Starts st;
    int acc = 0;
    for (int i = 0; i < NSCALES; i++) {
        st.blkStart[i] = acc;
        int s = 3 + 2 * i, s2 = s * s;
        acc += (IMGS_PER_SCALE * s2 + CHUNKPX - 1) / CHUNKPX;
    }

    int* wsC2  = (int*)d_ws;                    // 2 slots per image
    int* wsCnt = wsC2 + 2 * TOTAL_IMGS;
    int* wsN   = wsCnt + TOTAL_IMGS;
    int* wsM   = wsN + TOTAL_IMGS;

    count_kernel<<<acc, THREADS, 0, stream>>>(ptrs, st, wsC2);
    cc_kernel<<<TOTAL_IMGS / 64, THREADS, 0, stream>>>(ptrs, wsC2, wsCnt, wsN, wsM);
    final_kernel<<<NSCALES, THREADS, 0, stream>>>(wsCnt, wsN, wsM, (float*)d_out);
}